// Round 6
// baseline (1044.060 us; speedup 1.0000x reference)
//
#include <hip/hip_runtime.h>

#define B_ 4
#define T_ 2048
#define D_ 1024
#define HS_ 64

typedef __attribute__((ext_vector_type(4))) float f32x4;
typedef __attribute__((ext_vector_type(8))) short bf16x8;
typedef __attribute__((ext_vector_type(4))) unsigned short u16x4;
typedef __attribute__((ext_vector_type(4))) unsigned int u32x4;

__device__ __forceinline__ unsigned short f2bf(float f) {
  unsigned int u = __float_as_uint(f);
  u += 0x7FFFu + ((u >> 16) & 1u);   // RNE
  return (unsigned short)(u >> 16);
}
__device__ __forceinline__ float bf2f(unsigned short s) {
  return __uint_as_float(((unsigned int)s) << 16);
}

// ---------------------------------------------------------------------------
// kconv: transposed bf16 hi/lo split weights wT[192][1024].
// cols 0-63 = wq, 64-127 = 8*wk (score scale folded), 128-191 = wv.
// ---------------------------------------------------------------------------
__global__ void kconv_kernel(const float* __restrict__ wq, const float* __restrict__ wk,
                             const float* __restrict__ wv,
                             unsigned short* __restrict__ wTh, unsigned short* __restrict__ wTl) {
  int gid = blockIdx.x * 256 + threadIdx.x;   // < 192*1024
  int n = gid >> 10, d = gid & 1023;
  float v;
  if (n < 64)        v = wq[d * 64 + n];
  else if (n < 128)  v = 8.0f * wk[d * 64 + (n - 64)];
  else               v = wv[d * 64 + (n - 128)];
  unsigned short h = f2bf(v);
  wTh[gid] = h;
  wTl[gid] = f2bf(v - __uint_as_float(((unsigned int)h) << 16));
}

// ---------------------------------------------------------------------------
// kproj: C[8192][192] = x * wcat via split-bf16 MFMA (fp32-grade).
// Outputs: qw fp32 [B][T][64]; qhb/qlb bf16 hi/lo of q; khb/klb bf16 hi/lo
// of 8*k (for the S0 MFMA kernel); vbw bf16 [B][T][64].
// ---------------------------------------------------------------------------
__global__ __launch_bounds__(256) void kproj_kernel(
    const float* __restrict__ x, const unsigned short* __restrict__ wTh,
    const unsigned short* __restrict__ wTl,
    const float* __restrict__ bq, const float* __restrict__ bk, const float* __restrict__ bv,
    float* __restrict__ qw,
    unsigned short* __restrict__ qhb, unsigned short* __restrict__ qlb,
    unsigned short* __restrict__ khb, unsigned short* __restrict__ klb,
    unsigned short* __restrict__ vbw) {
  __shared__ unsigned short xh[32 * 32], xl[32 * 32];
  __shared__ unsigned short wh[192 * 32], wl[192 * 32];
  const int tid = threadIdx.x;
  const int m0 = blockIdx.x * 32;
  const int lane = tid & 63, wid = tid >> 6;
  const int mf = wid & 1, np = wid >> 1;
  const int r15 = lane & 15, u = lane >> 4;

  f32x4 xv;
  f32x4 wvh[3], wvl[3];
  auto issue = [&](int k0) {
    xv = *(const f32x4*)&x[(m0 + (tid >> 3)) * 1024 + k0 + (tid & 7) * 4];
#pragma unroll
    for (int i = 0; i < 3; ++i) {
      int c8 = i * 256 + tid;
      wvh[i] = *(const f32x4*)&wTh[(c8 >> 2) * 1024 + k0 + (c8 & 3) * 8];
      wvl[i] = *(const f32x4*)&wTl[(c8 >> 2) * 1024 + k0 + (c8 & 3) * 8];
    }
  };
  auto commit = [&]() {
    u16x4 hhv, llv;
#pragma unroll
    for (int c = 0; c < 4; ++c) {
      unsigned short h = f2bf(xv[c]);
      hhv[c] = h;
      llv[c] = f2bf(xv[c] - __uint_as_float(((unsigned int)h) << 16));
    }
    *(u16x4*)&xh[(tid >> 3) * 32 + (tid & 7) * 4] = hhv;
    *(u16x4*)&xl[(tid >> 3) * 32 + (tid & 7) * 4] = llv;
#pragma unroll
    for (int i = 0; i < 3; ++i) {
      int c8 = i * 256 + tid;
      *(f32x4*)&wh[c8 * 8] = wvh[i];
      *(f32x4*)&wl[c8 * 8] = wvl[i];
    }
  };

  f32x4 z = {0.f, 0.f, 0.f, 0.f};
  f32x4 acc[6] = {z, z, z, z, z, z};
  issue(0);
  for (int kt = 0; kt < 32; ++kt) {
    __syncthreads();
    commit();
    __syncthreads();
    if (kt + 1 < 32) issue((kt + 1) * 32);
    bf16x8 ah = *(const bf16x8*)&xh[(mf * 16 + r15) * 32 + u * 8];
    bf16x8 al = *(const bf16x8*)&xl[(mf * 16 + r15) * 32 + u * 8];
#pragma unroll
    for (int nf = 0; nf < 6; ++nf) {
      int nr = np * 96 + nf * 16 + r15;
      bf16x8 bh = *(const bf16x8*)&wh[nr * 32 + u * 8];
      bf16x8 bl = *(const bf16x8*)&wl[nr * 32 + u * 8];
      acc[nf] = __builtin_amdgcn_mfma_f32_16x16x32_bf16(ah, bh, acc[nf], 0, 0, 0);
      acc[nf] = __builtin_amdgcn_mfma_f32_16x16x32_bf16(ah, bl, acc[nf], 0, 0, 0);
      acc[nf] = __builtin_amdgcn_mfma_f32_16x16x32_bf16(al, bh, acc[nf], 0, 0, 0);
    }
  }
#pragma unroll
  for (int nf = 0; nf < 6; ++nf) {
    const int n = np * 96 + nf * 16 + r15;
#pragma unroll
    for (int r = 0; r < 4; ++r) {
      const int m = m0 + mf * 16 + u * 4 + r;
      float val = acc[nf][r];
      if (n < 64) {
        float qv = val + bq[n];
        qw[m * 64 + n] = qv;
        unsigned short h = f2bf(qv);
        qhb[m * 64 + n] = h;
        qlb[m * 64 + n] = f2bf(qv - __uint_as_float(((unsigned int)h) << 16));
      } else if (n < 128) {
        float kv = val + 8.0f * bk[n - 64];
        unsigned short h = f2bf(kv);
        khb[m * 64 + (n - 64)] = h;
        klb[m * 64 + (n - 64)] = f2bf(kv - __uint_as_float(((unsigned int)h) << 16));
      } else {
        int h = n - 128;
        vbw[m * 64 + h] = f2bf(val + bv[h]);
      }
    }
  }
}

// ---------------------------------------------------------------------------
// kqk: S0[t][v][b] = q[b,t,:]·k8[b,v,:] via split-bf16 MFMA (fp32-grade).
// Block = 4 waves; wave tile = 16t x 64v x 4b. No LDS, frags from global
// (q/k bf16 splits are L2/L3-hot). Output layout b-fastest so kfused reads
// are lane-contiguous and the epilogue stores are dwordx4.
// ---------------------------------------------------------------------------
__global__ __launch_bounds__(256, 2) void kqk_kernel(
    const unsigned short* __restrict__ qhb, const unsigned short* __restrict__ qlb,
    const unsigned short* __restrict__ khb, const unsigned short* __restrict__ klb,
    float* __restrict__ S0L) {
  const int tid = threadIdx.x;
  const int wid = tid >> 6, lane = tid & 63;
  const int r15 = lane & 15, u = lane >> 4;
  const int t0 = (blockIdx.x >> 3) * 16;
  const int v0 = (blockIdx.x & 7) * 256 + wid * 64;

  // A fragments: q rows t0+r15, all 4 batches, 2 k-steps, hi+lo
  bf16x8 ah[4][2], al[4][2];
#pragma unroll
  for (int b = 0; b < 4; ++b)
#pragma unroll
    for (int ks = 0; ks < 2; ++ks) {
      int off = ((b << 11) + t0 + r15) * 64 + ks * 32 + u * 8;
      ah[b][ks] = *(const bf16x8*)&qhb[off];
      al[b][ks] = *(const bf16x8*)&qlb[off];
    }

  f32x4 z = {0.f, 0.f, 0.f, 0.f};
  f32x4 acc[4][4] = {{z,z,z,z},{z,z,z,z},{z,z,z,z},{z,z,z,z}};  // [s][b]

#pragma unroll
  for (int s = 0; s < 4; ++s) {
    const int v1 = v0 + s * 16;
    bf16x8 bh[4][2], bl[4][2];
#pragma unroll
    for (int b = 0; b < 4; ++b)
#pragma unroll
      for (int ks = 0; ks < 2; ++ks) {
        int off = ((b << 11) + v1 + r15) * 64 + ks * 32 + u * 8;
        bh[b][ks] = *(const bf16x8*)&khb[off];
        bl[b][ks] = *(const bf16x8*)&klb[off];
      }
#pragma unroll
    for (int b = 0; b < 4; ++b)
#pragma unroll
      for (int ks = 0; ks < 2; ++ks) {
        acc[s][b] = __builtin_amdgcn_mfma_f32_16x16x32_bf16(ah[b][ks], bh[b][ks], acc[s][b], 0, 0, 0);
        acc[s][b] = __builtin_amdgcn_mfma_f32_16x16x32_bf16(ah[b][ks], bl[b][ks], acc[s][b], 0, 0, 0);
        acc[s][b] = __builtin_amdgcn_mfma_f32_16x16x32_bf16(al[b][ks], bh[b][ks], acc[s][b], 0, 0, 0);
      }
  }
  // epilogue: C row (t) = t0 + u*4 + r, col (v) = v1 + r15; pack b into f32x4
#pragma unroll
  for (int s = 0; s < 4; ++s) {
#pragma unroll
    for (int r = 0; r < 4; ++r) {
      f32x4 pk = {acc[s][0][r], acc[s][1][r], acc[s][2][r], acc[s][3][r]};
      size_t t = (size_t)(t0 + u * 4 + r);
      size_t v = (size_t)(v0 + s * 16 + r15);
      *(f32x4*)&S0L[(t * 2048 + v) * 4] = pk;
    }
  }
}

// ---------------------------------------------------------------------------
// kfused: flash attention over one v-half. Block = 8t x 4b, 16-v phases
// (64 phases, 1 raw barrier each — R5's proven protocol). Scores:
// s = S0L[t][v][b] (precomputed QK^T) + q·rel with rel streamed global->reg.
// LDS holds only the V tile (dbuf, pad-74: 2-way banks = free).
// T13 defer-rescale THR=5. All arrays statically indexed (rule #20).
// ---------------------------------------------------------------------------
__global__ __launch_bounds__(256, 2) void kfused(
    const float* __restrict__ qw, const float* __restrict__ S0L,
    const unsigned short* __restrict__ vbw, const float* __restrict__ rel,
    float* __restrict__ Oh, float* __restrict__ ml2) {
  __shared__ unsigned short vt_[2][64 * 74];  // V tile [b*16+v][74]  18944 B
  const int tid = threadIdx.x;
  const int tt = blockIdx.x >> 1, vh = blockIdx.x & 1;
  const int t0 = tt * 8;
  const int vbase = vh * 1024;
  const int wid = tid >> 6;
  const int tl = (tid >> 5) & 1;
  const int vl = (tid >> 2) & 7;
  const int hq = tid & 3;
  const int tloc = wid * 2 + tl;
  const int tg = t0 + tloc;

  // q in registers: 4 batches x this lane's h-quarter (16 h)
  f32x4 qr[4][4];
#pragma unroll
  for (int b = 0; b < 4; ++b)
#pragma unroll
    for (int j = 0; j < 4; ++j)
      qr[b][j] = *(const f32x4*)&qw[((b << 11) + tg) * 64 + hq * 16 + j * 4];

  const float* relrow = rel + (size_t)tg * 131072 + hq * 16;
  const float* s0row = S0L + (size_t)tg * 8192 + hq;   // + v*4

  f32x4 rA[8], rB[8];      // rel ping-pong: rows (vl) and (vl+8) of a 16v tile
  float s0A[2], s0B[2];    // S0 ping-pong for (vl, vl+8)
  f32x4 stv[2];            // V staging (8 KB tile / 256 thr)

#define ISSUE_REL(DST, S0D, VT) do {                                      \
    const float* p0_ = relrow + (size_t)((VT) + vl) * 64;                 \
    const float* p1_ = relrow + (size_t)((VT) + vl + 8) * 64;             \
    DST[0] = *(const f32x4*)(p0_);      DST[1] = *(const f32x4*)(p0_ + 4);\
    DST[2] = *(const f32x4*)(p0_ + 8);  DST[3] = *(const f32x4*)(p0_ +12);\
    DST[4] = *(const f32x4*)(p1_);      DST[5] = *(const f32x4*)(p1_ + 4);\
    DST[6] = *(const f32x4*)(p1_ + 8);  DST[7] = *(const f32x4*)(p1_ +12);\
    S0D[0] = s0row[((VT) + vl) * 4];                                      \
    S0D[1] = s0row[((VT) + vl + 8) * 4];                                  \
  } while (0)

  auto issue_v = [&](int vt) {
#pragma unroll
    for (int i = 0; i < 2; ++i) {              // V tile (bf16): 8KB
      int c8 = i * 256 + tid;
      int pr = c8 >> 3, cc = c8 & 7;           // row = b*16+vv
      stv[i] = *(const f32x4*)&vbw[(((pr >> 4) << 11) + vt + (pr & 15)) * 64 + cc * 8];
    }
  };
  auto commit_v = [&](int buf) {
#pragma unroll
    for (int i = 0; i < 2; ++i) {
      int c8 = i * 256 + tid;
      int pr = c8 >> 3, cc = c8 & 7;
      const u16x4* pv = (const u16x4*)&stv[i];
      *(u16x4*)&vt_[buf][pr * 74 + cc * 8] = pv[0];
      *(u16x4*)&vt_[buf][pr * 74 + cc * 8 + 4] = pv[1];
    }
  };

  float o[64];
#pragma unroll
  for (int h = 0; h < 64; ++h) o[h] = 0.0f;
  float mrun = -3.0e38f, lrun = 0.0f;

#define PHASE_BARRIER() do {                                              \
    asm volatile("s_waitcnt lgkmcnt(0)" ::: "memory");                    \
    __builtin_amdgcn_s_barrier();                                         \
    asm volatile("" ::: "memory");                                        \
  } while (0)

#define COMPUTE(RC, S0R, BUF) do {                                        \
    f32x4 z4 = {0.f, 0.f, 0.f, 0.f};                                      \
    f32x4 a0 = z4, a1 = z4, a2 = z4, a3 = z4;                             \
    f32x4 c0 = z4, c1 = z4, c2 = z4, c3 = z4;                             \
    _Pragma("unroll")                                                     \
    for (int j = 0; j < 4; ++j) {                                         \
      a0 += qr[0][j] * RC[j];                                             \
      a1 += qr[1][j] * RC[j];                                             \
      a2 += qr[2][j] * RC[j];                                             \
      a3 += qr[3][j] * RC[j];                                             \
      c0 += qr[0][j] * RC[4 + j];                                         \
      c1 += qr[1][j] * RC[4 + j];                                         \
      c2 += qr[2][j] * RC[4 + j];                                         \
      c3 += qr[3][j] * RC[4 + j];                                         \
    }                                                                     \
    float sa0 = a0[0] + a0[1] + a0[2] + a0[3];                            \
    float sa1 = a1[0] + a1[1] + a1[2] + a1[3];                            \
    float sa2 = a2[0] + a2[1] + a2[2] + a2[3];                            \
    float sa3 = a3[0] + a3[1] + a3[2] + a3[3];                            \
    float sb0 = c0[0] + c0[1] + c0[2] + c0[3];                            \
    float sb1 = c1[0] + c1[1] + c1[2] + c1[3];                            \
    float sb2 = c2[0] + c2[1] + c2[2] + c2[3];                            \
    float sb3 = c3[0] + c3[1] + c3[2] + c3[3];                            \
    sa0 += __shfl_xor(sa0, 1); sa0 += __shfl_xor(sa0, 2);                 \
    sa1 += __shfl_xor(sa1, 1); sa1 += __shfl_xor(sa1, 2);                 \
    sa2 += __shfl_xor(sa2, 1); sa2 += __shfl_xor(sa2, 2);                 \
    sa3 += __shfl_xor(sa3, 1); sa3 += __shfl_xor(sa3, 2);                 \
    sb0 += __shfl_xor(sb0, 1); sb0 += __shfl_xor(sb0, 2);                 \
    sb1 += __shfl_xor(sb1, 1); sb1 += __shfl_xor(sb1, 2);                 \
    sb2 += __shfl_xor(sb2, 1); sb2 += __shfl_xor(sb2, 2);                 \
    sb3 += __shfl_xor(sb3, 1); sb3 += __shfl_xor(sb3, 2);                 \
    float sA = ((hq == 0) ? sa0 : (hq == 1) ? sa1 : (hq == 2) ? sa2 : sa3) + S0R[0]; \
    float sB = ((hq == 0) ? sb0 : (hq == 1) ? sb1 : (hq == 2) ? sb2 : sb3) + S0R[1]; \
    float mx = fmaxf(sA, sB);                                             \
    mx = fmaxf(mx, __shfl_xor(mx, 4));                                    \
    mx = fmaxf(mx, __shfl_xor(mx, 8));                                    \
    mx = fmaxf(mx, __shfl_xor(mx, 16));                                   \
    if (__any(mx > mrun + 5.0f)) {       /* T13: rescale only on drift */ \
      float mnew = fmaxf(mrun, mx);                                       \
      float alpha = __expf(mrun - mnew);                                  \
      lrun *= alpha;                                                      \
      _Pragma("unroll")                                                   \
      for (int h = 0; h < 64; ++h) o[h] *= alpha;                         \
      mrun = mnew;                                                        \
    }                                                                     \
    float p0 = __expf(sA - mrun);                                         \
    float p1 = __expf(sB - mrun);                                         \
    float ps_ = p0 + p1;                                                  \
    ps_ += __shfl_xor(ps_, 4);                                            \
    ps_ += __shfl_xor(ps_, 8);                                            \
    ps_ += __shfl_xor(ps_, 16);                                           \
    lrun += ps_;                                                          \
    const unsigned short* vrA = &vt_[BUF][(hq * 16 + vl) * 74];           \
    const unsigned short* vrB = &vt_[BUF][(hq * 16 + vl + 8) * 74];       \
    _Pragma("unroll")                                                     \
    for (int k = 0; k < 16; ++k) {                                        \
      u16x4 va = *(const u16x4*)&vrA[k * 4];                              \
      u16x4 vb = *(const u16x4*)&vrB[k * 4];                              \
      o[k * 4 + 0] = fmaf(p0, bf2f(va[0]), o[k * 4 + 0]);                 \
      o[k * 4 + 1] = fmaf(p0, bf2f(va[1]), o[k * 4 + 1]);                 \
      o[k * 4 + 2] = fmaf(p0, bf2f(va[2]), o[k * 4 + 2]);                 \
      o[k * 4 + 3] = fmaf(p0, bf2f(va[3]), o[k * 4 + 3]);                 \
      o[k * 4 + 0] = fmaf(p1, bf2f(vb[0]), o[k * 4 + 0]);                 \
      o[k * 4 + 1] = fmaf(p1, bf2f(vb[1]), o[k * 4 + 1]);                 \
      o[k * 4 + 2] = fmaf(p1, bf2f(vb[2]), o[k * 4 + 2]);                 \
      o[k * 4 + 3] = fmaf(p1, bf2f(vb[3]), o[k * 4 + 3]);                 \
    }                                                                     \
  } while (0)

  // prologue: tile 0 into rA/s0A + LDS buf 0
  ISSUE_REL(rA, s0A, vbase);
  issue_v(vbase);
  commit_v(0);
  PHASE_BARRIER();

  int cur = 0;
  for (int it2 = 0; it2 < 32; ++it2) {
    const int vt = vbase + it2 * 32;
    // phase A: consume rA/s0A/buf cur; prefetch next 16v into rB/s0B/buf^1
    {
      ISSUE_REL(rB, s0B, vt + 16);
      issue_v(vt + 16);
      COMPUTE(rA, s0A, cur);
      commit_v(cur ^ 1);     // other buffer: readers finished at last barrier
      PHASE_BARRIER();
      cur ^= 1;
    }
    // phase B
    {
      const bool more = (it2 + 1 < 32);
      if (more) {
        ISSUE_REL(rA, s0A, vt + 32);
        issue_v(vt + 32);
      }
      COMPUTE(rB, s0B, cur);
      if (more) commit_v(cur ^ 1);
      PHASE_BARRIER();
      cur ^= 1;
    }
  }

  // reduce-scatter O over the 8 v-lanes: lane vl ends with o[vl*8..+7]
  float n32[32];
#pragma unroll
  for (int j = 0; j < 32; ++j) {
    float send = (vl & 4) ? o[j] : o[j + 32];
    float t = __shfl_xor(send, 16);
    float keep = (vl & 4) ? o[j + 32] : o[j];
    n32[j] = keep + t;
  }
  float n16[16];
#pragma unroll
  for (int j = 0; j < 16; ++j) {
    float send = (vl & 2) ? n32[j] : n32[j + 16];
    float t = __shfl_xor(send, 8);
    float keep = (vl & 2) ? n32[j + 16] : n32[j];
    n16[j] = keep + t;
  }
  float n8[8];
#pragma unroll
  for (int j = 0; j < 8; ++j) {
    float send = (vl & 1) ? n16[j] : n16[j + 8];
    float t = __shfl_xor(send, 4);
    float keep = (vl & 1) ? n16[j + 8] : n16[j];
    n8[j] = keep + t;
  }

  const int orow = (vh * 4 + hq) * 2048 + tg;
  f32x4 w0 = {n8[0], n8[1], n8[2], n8[3]};
  f32x4 w1 = {n8[4], n8[5], n8[6], n8[7]};
  *(f32x4*)&Oh[orow * 64 + vl * 8] = w0;
  *(f32x4*)&Oh[orow * 64 + vl * 8 + 4] = w1;
  if (vl == 0) {
    ml2[orow * 2] = mrun;
    ml2[orow * 2 + 1] = lrun;
  }
#undef ISSUE_REL
#undef COMPUTE
#undef PHASE_BARRIER
}

// ---------------------------------------------------------------------------
// kcomb: merge the two v-half partials.
// ---------------------------------------------------------------------------
__global__ __launch_bounds__(256) void kcomb(
    const float* __restrict__ Oh, const float* __restrict__ ml2,
    float* __restrict__ O) {
  int gid = blockIdx.x * 256 + threadIdx.x;    // 8192 rows * 16 h-quads
  int row = gid >> 4, hc = gid & 15;
  float m0 = ml2[row * 2], l0 = ml2[row * 2 + 1];
  float m1 = ml2[(8192 + row) * 2], l1 = ml2[(8192 + row) * 2 + 1];
  float m = fmaxf(m0, m1);
  float c0 = __expf(m0 - m), c1 = __expf(m1 - m);
  float linv = 1.0f / (c0 * l0 + c1 * l1);
  f32x4 o0 = *(const f32x4*)&Oh[row * 64 + hc * 4];
  f32x4 o1 = *(const f32x4*)&Oh[(8192 + row) * 64 + hc * 4];
  f32x4 r;
#pragma unroll
  for (int j = 0; j < 4; ++j) r[j] = (c0 * o0[j] + c1 * o1[j]) * linv;
  *(f32x4*)&O[row * 64 + hc * 4] = r;
}

// ---------------------------------------------------------------------------
extern "C" void kernel_launch(void* const* d_in, const int* in_sizes, int n_in,
                              void* d_out, int out_size, void* d_ws, size_t ws_size,
                              hipStream_t stream) {
  const float* x   = (const float*)d_in[0];
  const float* wq  = (const float*)d_in[1];
  const float* bq  = (const float*)d_in[2];
  const float* wk  = (const float*)d_in[3];
  const float* bk  = (const float*)d_in[4];
  const float* wv  = (const float*)d_in[5];
  const float* bv  = (const float*)d_in[6];
  const float* rel = (const float*)d_in[7];
  float* O = (float*)d_out;

  char* ws = (char*)d_ws;
  float* S0L           = (float*)(ws);                       // 67,108,864 B [t][v][b]
  // wTh/wTl overlap the head of S0L: consumed by kproj BEFORE kqk writes S0L
  unsigned short* wTh  = (unsigned short*)(ws);              //    393,216 B
  unsigned short* wTl  = (unsigned short*)(ws + 393216);     //    393,216 B
  float* qw            = (float*)(ws + 67108864);            //  2,097,152 B
  unsigned short* vbw  = (unsigned short*)(ws + 69206016);   //  1,048,576 B
  unsigned short* qhb  = (unsigned short*)(ws + 70254592);   //  1,048,576 B
  unsigned short* qlb  = (unsigned short*)(ws + 71303168);   //  1,048,576 B
  unsigned short* khb  = (unsigned short*)(ws + 72351744);   //  1,048,576 B
  unsigned short* klb  = (unsigned short*)(ws + 73400320);   //  1,048,576 B
  float* Oh            = (float*)(ws + 74448896);            //  4,194,304 B
  float* ml2           = (float*)(ws + 78643200);            //    131,072 B
  // total ws usage: ~78.8 MB

  kconv_kernel<<<dim3(768), dim3(256), 0, stream>>>(wq, wk, wv, wTh, wTl);
  kproj_kernel<<<dim3(256), dim3(256), 0, stream>>>(x, wTh, wTl, bq, bk, bv,
                                                    qw, qhb, qlb, khb, klb, vbw);
  kqk_kernel<<<dim3(1024), dim3(256), 0, stream>>>(qhb, qlb, khb, klb, S0L);
  kfused<<<dim3(512), dim3(256), 0, stream>>>(qw, S0L, vbw, rel, Oh, ml2);
  kcomb<<<dim3(512), dim3(256), 0, stream>>>(Oh, ml2, O);
}

// Round 7
// 622.821 us; speedup vs baseline: 1.6763x; 1.6763x over previous
//
#include <hip/hip_runtime.h>

#define B_ 4
#define T_ 2048
#define D_ 1024
#define HS_ 64

typedef __attribute__((ext_vector_type(4))) float f32x4;
typedef __attribute__((ext_vector_type(8))) short bf16x8;
typedef __attribute__((ext_vector_type(4))) unsigned short u16x4;
typedef __attribute__((ext_vector_type(4))) unsigned int u32x4;

__device__ __forceinline__ unsigned short f2bf(float f) {
  unsigned int u = __float_as_uint(f);
  u += 0x7FFFu + ((u >> 16) & 1u);   // RNE
  return (unsigned short)(u >> 16);
}
__device__ __forceinline__ float bf2f(unsigned short s) {
  return __uint_as_float(((unsigned int)s) << 16);
}

// ---------------------------------------------------------------------------
// kconv: transposed bf16 hi/lo split weights wT[192][1024].
// cols 0-63 = wq, 64-127 = 8*wk (score scale folded), 128-191 = wv.
// ---------------------------------------------------------------------------
__global__ void kconv_kernel(const float* __restrict__ wq, const float* __restrict__ wk,
                             const float* __restrict__ wv,
                             unsigned short* __restrict__ wTh, unsigned short* __restrict__ wTl) {
  int gid = blockIdx.x * 256 + threadIdx.x;   // < 192*1024
  int n = gid >> 10, d = gid & 1023;
  float v;
  if (n < 64)        v = wq[d * 64 + n];
  else if (n < 128)  v = 8.0f * wk[d * 64 + (n - 64)];
  else               v = wv[d * 64 + (n - 128)];
  unsigned short h = f2bf(v);
  wTh[gid] = h;
  wTl[gid] = f2bf(v - __uint_as_float(((unsigned int)h) << 16));
}

// ---------------------------------------------------------------------------
// kproj: C[8192][192] = x * wcat via split-bf16 MFMA (fp32-grade).
// Outputs: qw fp32 [B][T][64]; qhb/qlb, khb/klb bf16 hi/lo splits of q and
// 8*k (inputs to the S0 MFMA kernel); vbw bf16 [B][T][64].
// ---------------------------------------------------------------------------
__global__ __launch_bounds__(256) void kproj_kernel(
    const float* __restrict__ x, const unsigned short* __restrict__ wTh,
    const unsigned short* __restrict__ wTl,
    const float* __restrict__ bq, const float* __restrict__ bk, const float* __restrict__ bv,
    float* __restrict__ qw,
    unsigned short* __restrict__ qhb, unsigned short* __restrict__ qlb,
    unsigned short* __restrict__ khb, unsigned short* __restrict__ klb,
    unsigned short* __restrict__ vbw) {
  __shared__ unsigned short xh[32 * 32], xl[32 * 32];
  __shared__ unsigned short wh[192 * 32], wl[192 * 32];
  const int tid = threadIdx.x;
  const int m0 = blockIdx.x * 32;
  const int lane = tid & 63, wid = tid >> 6;
  const int mf = wid & 1, np = wid >> 1;
  const int r15 = lane & 15, u = lane >> 4;

  f32x4 xv;
  f32x4 wvh[3], wvl[3];
  auto issue = [&](int k0) {
    xv = *(const f32x4*)&x[(m0 + (tid >> 3)) * 1024 + k0 + (tid & 7) * 4];
#pragma unroll
    for (int i = 0; i < 3; ++i) {
      int c8 = i * 256 + tid;
      wvh[i] = *(const f32x4*)&wTh[(c8 >> 2) * 1024 + k0 + (c8 & 3) * 8];
      wvl[i] = *(const f32x4*)&wTl[(c8 >> 2) * 1024 + k0 + (c8 & 3) * 8];
    }
  };
  auto commit = [&]() {
    u16x4 hhv, llv;
#pragma unroll
    for (int c = 0; c < 4; ++c) {
      unsigned short h = f2bf(xv[c]);
      hhv[c] = h;
      llv[c] = f2bf(xv[c] - __uint_as_float(((unsigned int)h) << 16));
    }
    *(u16x4*)&xh[(tid >> 3) * 32 + (tid & 7) * 4] = hhv;
    *(u16x4*)&xl[(tid >> 3) * 32 + (tid & 7) * 4] = llv;
#pragma unroll
    for (int i = 0; i < 3; ++i) {
      int c8 = i * 256 + tid;
      *(f32x4*)&wh[c8 * 8] = wvh[i];
      *(f32x4*)&wl[c8 * 8] = wvl[i];
    }
  };

  f32x4 z = {0.f, 0.f, 0.f, 0.f};
  f32x4 acc[6] = {z, z, z, z, z, z};
  issue(0);
  for (int kt = 0; kt < 32; ++kt) {
    __syncthreads();
    commit();
    __syncthreads();
    if (kt + 1 < 32) issue((kt + 1) * 32);
    bf16x8 ah = *(const bf16x8*)&xh[(mf * 16 + r15) * 32 + u * 8];
    bf16x8 al = *(const bf16x8*)&xl[(mf * 16 + r15) * 32 + u * 8];
#pragma unroll
    for (int nf = 0; nf < 6; ++nf) {
      int nr = np * 96 + nf * 16 + r15;
      bf16x8 bh = *(const bf16x8*)&wh[nr * 32 + u * 8];
      bf16x8 bl = *(const bf16x8*)&wl[nr * 32 + u * 8];
      acc[nf] = __builtin_amdgcn_mfma_f32_16x16x32_bf16(ah, bh, acc[nf], 0, 0, 0);
      acc[nf] = __builtin_amdgcn_mfma_f32_16x16x32_bf16(ah, bl, acc[nf], 0, 0, 0);
      acc[nf] = __builtin_amdgcn_mfma_f32_16x16x32_bf16(al, bh, acc[nf], 0, 0, 0);
    }
  }
#pragma unroll
  for (int nf = 0; nf < 6; ++nf) {
    const int n = np * 96 + nf * 16 + r15;
#pragma unroll
    for (int r = 0; r < 4; ++r) {
      const int m = m0 + mf * 16 + u * 4 + r;
      float val = acc[nf][r];
      if (n < 64) {
        float qv = val + bq[n];
        qw[m * 64 + n] = qv;
        unsigned short h = f2bf(qv);
        qhb[m * 64 + n] = h;
        qlb[m * 64 + n] = f2bf(qv - __uint_as_float(((unsigned int)h) << 16));
      } else if (n < 128) {
        float kv = val + 8.0f * bk[n - 64];
        unsigned short h = f2bf(kv);
        khb[m * 64 + (n - 64)] = h;
        klb[m * 64 + (n - 64)] = f2bf(kv - __uint_as_float(((unsigned int)h) << 16));
      } else {
        int h = n - 128;
        vbw[m * 64 + h] = f2bf(val + bv[h]);
      }
    }
  }
}

// ---------------------------------------------------------------------------
// kqk: S0[t][v][b] = q[b,t,:]·k8[b,v,:] via split-bf16 MFMA (fp32-grade).
// b-fastest output layout -> kfused reads are lane-contiguous.
// ---------------------------------------------------------------------------
__global__ __launch_bounds__(256, 2) void kqk_kernel(
    const unsigned short* __restrict__ qhb, const unsigned short* __restrict__ qlb,
    const unsigned short* __restrict__ khb, const unsigned short* __restrict__ klb,
    float* __restrict__ S0L) {
  const int tid = threadIdx.x;
  const int wid = tid >> 6, lane = tid & 63;
  const int r15 = lane & 15, u = lane >> 4;
  const int t0 = (blockIdx.x >> 3) * 16;
  const int v0 = (blockIdx.x & 7) * 256 + wid * 64;

  bf16x8 ah[4][2], al[4][2];
#pragma unroll
  for (int b = 0; b < 4; ++b)
#pragma unroll
    for (int ks = 0; ks < 2; ++ks) {
      int off = ((b << 11) + t0 + r15) * 64 + ks * 32 + u * 8;
      ah[b][ks] = *(const bf16x8*)&qhb[off];
      al[b][ks] = *(const bf16x8*)&qlb[off];
    }

  f32x4 z = {0.f, 0.f, 0.f, 0.f};
  f32x4 acc[4][4] = {{z,z,z,z},{z,z,z,z},{z,z,z,z},{z,z,z,z}};  // [s][b]

#pragma unroll
  for (int s = 0; s < 4; ++s) {
    const int v1 = v0 + s * 16;
    bf16x8 bh[4][2], bl[4][2];
#pragma unroll
    for (int b = 0; b < 4; ++b)
#pragma unroll
      for (int ks = 0; ks < 2; ++ks) {
        int off = ((b << 11) + v1 + r15) * 64 + ks * 32 + u * 8;
        bh[b][ks] = *(const bf16x8*)&khb[off];
        bl[b][ks] = *(const bf16x8*)&klb[off];
      }
#pragma unroll
    for (int b = 0; b < 4; ++b)
#pragma unroll
      for (int ks = 0; ks < 2; ++ks) {
        acc[s][b] = __builtin_amdgcn_mfma_f32_16x16x32_bf16(ah[b][ks], bh[b][ks], acc[s][b], 0, 0, 0);
        acc[s][b] = __builtin_amdgcn_mfma_f32_16x16x32_bf16(ah[b][ks], bl[b][ks], acc[s][b], 0, 0, 0);
        acc[s][b] = __builtin_amdgcn_mfma_f32_16x16x32_bf16(al[b][ks], bh[b][ks], acc[s][b], 0, 0, 0);
      }
  }
#pragma unroll
  for (int s = 0; s < 4; ++s) {
#pragma unroll
    for (int r = 0; r < 4; ++r) {
      f32x4 pk = {acc[s][0][r], acc[s][1][r], acc[s][2][r], acc[s][3][r]};
      size_t t = (size_t)(t0 + u * 4 + r);
      size_t v = (size_t)(v0 + s * 16 + r15);
      *(f32x4*)&S0L[(t * 2048 + v) * 4] = pk;
    }
  }
}

// ---------------------------------------------------------------------------
// kfused: flash attention over one v-half. Block = 8t x 4b, 8-v phases,
// raw-barrier protocol (R5). Scores: s = S0L[t][v][b] + q·rel (rel direct
// global->reg). LDS: only the 4KB V tile (dbuf, pad-74 conflict-free).
// Register diet: o[32] h-half accumulator + partner-p shfl exchange
// (live-set ~120 VGPR, away from the ~170 spill cliff seen R2/R4/R6).
// T13 defer-rescale THR=5. All arrays statically indexed (rule #20).
// ---------------------------------------------------------------------------
__global__ __launch_bounds__(256, 2) void kfused(
    const float* __restrict__ qw, const float* __restrict__ S0L,
    const unsigned short* __restrict__ vbw, const float* __restrict__ rel,
    float* __restrict__ Oh, float* __restrict__ ml2) {
  __shared__ unsigned short vt_[2][32 * 74];  // V tile [b*8+v][74]  9472 B
  const int tid = threadIdx.x;
  const int tt = blockIdx.x >> 1, vh = blockIdx.x & 1;
  const int t0 = tt * 8;
  const int vbase = vh * 1024;
  const int wid = tid >> 6;
  const int tl = (tid >> 5) & 1;
  const int vl = (tid >> 2) & 7;
  const int hq = tid & 3;
  const int tloc = wid * 2 + tl;
  const int tg = t0 + tloc;
  const int hbase = (vl & 1) * 32;      // this thread's h-half for PV

  // q in registers: 4 batches x this lane's h-quarter (16 h)
  f32x4 qr[4][4];
#pragma unroll
  for (int b = 0; b < 4; ++b)
#pragma unroll
    for (int j = 0; j < 4; ++j)
      qr[b][j] = *(const f32x4*)&qw[((b << 11) + tg) * 64 + hq * 16 + j * 4];

  const float* relrow = rel + (size_t)tg * 131072 + hq * 16;
  const float* s0p = S0L + (size_t)tg * 8192 + hq;   // + v*4

  f32x4 rA[4], rB[4];      // rel ping-pong (per-thread-private data)
  float s0A, s0B;          // S0 ping-pong (this thread's batch hq, v=vl)
  f32x4 stv;               // V staging (4KB tile / 256 thr)

#define ISSUE_REL(DST, S0D, VT) do {                                      \
    const float* p_ = relrow + (size_t)((VT) + vl) * 64;                  \
    DST[0] = *(const f32x4*)(p_);                                         \
    DST[1] = *(const f32x4*)(p_ + 4);                                     \
    DST[2] = *(const f32x4*)(p_ + 8);                                     \
    DST[3] = *(const f32x4*)(p_ + 12);                                    \
    S0D = s0p[((VT) + vl) * 4];                                           \
  } while (0)

  auto issue_v = [&](int vt) {
    int pr = tid >> 3, cc = tid & 7;           // row = b*8+vv
    stv = *(const f32x4*)&vbw[(((pr >> 3) << 11) + vt + (pr & 7)) * 64 + cc * 8];
  };
  auto commit_v = [&](int buf) {
    int pr = tid >> 3, cc = tid & 7;
    const u16x4* pv = (const u16x4*)&stv;
    *(u16x4*)&vt_[buf][pr * 74 + cc * 8] = pv[0];
    *(u16x4*)&vt_[buf][pr * 74 + cc * 8 + 4] = pv[1];
  };

  float o[32];
#pragma unroll
  for (int h = 0; h < 32; ++h) o[h] = 0.0f;
  float mrun = -3.0e38f, lrun = 0.0f;

#define PHASE_BARRIER() do {                                              \
    asm volatile("s_waitcnt lgkmcnt(0)" ::: "memory");                    \
    __builtin_amdgcn_s_barrier();                                         \
    asm volatile("" ::: "memory");                                        \
  } while (0)

#define COMPUTE(RC, S0S, BUF) do {                                        \
    f32x4 z4 = {0.f, 0.f, 0.f, 0.f};                                      \
    f32x4 a0 = z4, a1 = z4, a2 = z4, a3 = z4;                             \
    _Pragma("unroll")                                                     \
    for (int j = 0; j < 4; ++j) {                                         \
      a0 += qr[0][j] * RC[j];                                             \
      a1 += qr[1][j] * RC[j];                                             \
      a2 += qr[2][j] * RC[j];                                             \
      a3 += qr[3][j] * RC[j];                                             \
    }                                                                     \
    float s0_ = a0[0] + a0[1] + a0[2] + a0[3];                            \
    float s1_ = a1[0] + a1[1] + a1[2] + a1[3];                            \
    float s2_ = a2[0] + a2[1] + a2[2] + a2[3];                            \
    float s3_ = a3[0] + a3[1] + a3[2] + a3[3];                            \
    s0_ += __shfl_xor(s0_, 1); s0_ += __shfl_xor(s0_, 2);                 \
    s1_ += __shfl_xor(s1_, 1); s1_ += __shfl_xor(s1_, 2);                 \
    s2_ += __shfl_xor(s2_, 1); s2_ += __shfl_xor(s2_, 2);                 \
    s3_ += __shfl_xor(s3_, 1); s3_ += __shfl_xor(s3_, 2);                 \
    float s = ((hq == 0) ? s0_ : (hq == 1) ? s1_ : (hq == 2) ? s2_ : s3_) \
              + S0S;                                                      \
    float mx = s;                                                         \
    mx = fmaxf(mx, __shfl_xor(mx, 4));                                    \
    mx = fmaxf(mx, __shfl_xor(mx, 8));                                    \
    mx = fmaxf(mx, __shfl_xor(mx, 16));                                   \
    if (__any(mx > mrun + 5.0f)) {       /* T13: rescale only on drift */ \
      float mnew = fmaxf(mrun, mx);                                       \
      float alpha = __expf(mrun - mnew);                                  \
      lrun *= alpha;                                                      \
      _Pragma("unroll")                                                   \
      for (int h = 0; h < 32; ++h) o[h] *= alpha;                         \
      mrun = mnew;                                                        \
    }                                                                     \
    float p = __expf(s - mrun);                                           \
    float ps_ = p;                                                        \
    ps_ += __shfl_xor(ps_, 4);                                            \
    ps_ += __shfl_xor(ps_, 8);                                            \
    ps_ += __shfl_xor(ps_, 16);                                           \
    lrun += ps_;                                                          \
    float pp = __shfl_xor(p, 4);         /* partner lane vl^1's p */      \
    const unsigned short* vo = &vt_[BUF][(hq * 8 + vl) * 74 + hbase];     \
    const unsigned short* vp = &vt_[BUF][(hq * 8 + (vl ^ 1)) * 74 + hbase]; \
    _Pragma("unroll")                                                     \
    for (int k = 0; k < 8; ++k) {                                         \
      u16x4 va = *(const u16x4*)&vo[k * 4];                               \
      u16x4 vb = *(const u16x4*)&vp[k * 4];                               \
      o[k * 4 + 0] = fmaf(p, bf2f(va[0]), fmaf(pp, bf2f(vb[0]), o[k * 4 + 0])); \
      o[k * 4 + 1] = fmaf(p, bf2f(va[1]), fmaf(pp, bf2f(vb[1]), o[k * 4 + 1])); \
      o[k * 4 + 2] = fmaf(p, bf2f(va[2]), fmaf(pp, bf2f(vb[2]), o[k * 4 + 2])); \
      o[k * 4 + 3] = fmaf(p, bf2f(va[3]), fmaf(pp, bf2f(vb[3]), o[k * 4 + 3])); \
    }                                                                     \
  } while (0)

  // prologue: tile 0 into rA/s0A + LDS buf 0
  ISSUE_REL(rA, s0A, vbase);
  issue_v(vbase);
  commit_v(0);
  PHASE_BARRIER();

  int cur = 0;
  for (int it2 = 0; it2 < 64; ++it2) {
    const int vt = vbase + it2 * 16;
    // phase A: consume rA/s0A/buf cur; prefetch (2*it2+1) into rB/s0B/buf^1
    {
      ISSUE_REL(rB, s0B, vt + 8);
      issue_v(vt + 8);
      COMPUTE(rA, s0A, cur);
      commit_v(cur ^ 1);     // other buffer: readers finished at last barrier
      PHASE_BARRIER();
      cur ^= 1;
    }
    // phase B
    {
      const bool more = (it2 + 1 < 64);
      if (more) {
        ISSUE_REL(rA, s0A, vt + 16);
        issue_v(vt + 16);
      }
      COMPUTE(rB, s0B, cur);
      if (more) commit_v(cur ^ 1);
      PHASE_BARRIER();
      cur ^= 1;
    }
  }

  // reduce-scatter o[32] over the 4 lanes sharing this h-half:
  // step 1: xor 8 (vl bit1), step 2: xor 16 (vl bit2)
  float n16[16];
#pragma unroll
  for (int j = 0; j < 16; ++j) {
    float send = (vl & 2) ? o[j] : o[j + 16];
    float t = __shfl_xor(send, 8);
    float keep = (vl & 2) ? o[j + 16] : o[j];
    n16[j] = keep + t;
  }
  float n8[8];
#pragma unroll
  for (int j = 0; j < 8; ++j) {
    float send = (vl & 4) ? n16[j] : n16[j + 8];
    float t = __shfl_xor(send, 16);
    float keep = (vl & 4) ? n16[j + 8] : n16[j];
    n8[j] = keep + t;
  }

  const int h0 = hbase + ((vl >> 1) & 1) * 16 + ((vl >> 2) & 1) * 8;
  const int orow = (vh * 4 + hq) * 2048 + tg;
  f32x4 w0 = {n8[0], n8[1], n8[2], n8[3]};
  f32x4 w1 = {n8[4], n8[5], n8[6], n8[7]};
  *(f32x4*)&Oh[orow * 64 + h0] = w0;
  *(f32x4*)&Oh[orow * 64 + h0 + 4] = w1;
  if (vl == 0) {
    ml2[orow * 2] = mrun;
    ml2[orow * 2 + 1] = lrun;
  }
#undef ISSUE_REL
#undef COMPUTE
#undef PHASE_BARRIER
}

// ---------------------------------------------------------------------------
// kcomb: merge the two v-half partials.
// ---------------------------------------------------------------------------
__global__ __launch_bounds__(256) void kcomb(
    const float* __restrict__ Oh, const float* __restrict__ ml2,
    float* __restrict__ O) {
  int gid = blockIdx.x * 256 + threadIdx.x;    // 8192 rows * 16 h-quads
  int row = gid >> 4, hc = gid & 15;
  float m0 = ml2[row * 2], l0 = ml2[row * 2 + 1];
  float m1 = ml2[(8192 + row) * 2], l1 = ml2[(8192 + row) * 2 + 1];
  float m = fmaxf(m0, m1);
  float c0 = __expf(m0 - m), c1 = __expf(m1 - m);
  float linv = 1.0f / (c0 * l0 + c1 * l1);
  f32x4 o0 = *(const f32x4*)&Oh[row * 64 + hc * 4];
  f32x4 o1 = *(const f32x4*)&Oh[(8192 + row) * 64 + hc * 4];
  f32x4 r;
#pragma unroll
  for (int j = 0; j < 4; ++j) r[j] = (c0 * o0[j] + c1 * o1[j]) * linv;
  *(f32x4*)&O[row * 64 + hc * 4] = r;
}

// ---------------------------------------------------------------------------
extern "C" void kernel_launch(void* const* d_in, const int* in_sizes, int n_in,
                              void* d_out, int out_size, void* d_ws, size_t ws_size,
                              hipStream_t stream) {
  const float* x   = (const float*)d_in[0];
  const float* wq  = (const float*)d_in[1];
  const float* bq  = (const float*)d_in[2];
  const float* wk  = (const float*)d_in[3];
  const float* bk  = (const float*)d_in[4];
  const float* wv  = (const float*)d_in[5];
  const float* bv  = (const float*)d_in[6];
  const float* rel = (const float*)d_in[7];
  float* O = (float*)d_out;

  char* ws = (char*)d_ws;
  float* S0L           = (float*)(ws);                       // 67,108,864 B [t][v][b]
  // wTh/wTl overlap the head of S0L: consumed by kproj BEFORE kqk writes S0L
  unsigned short* wTh  = (unsigned short*)(ws);              //    393,216 B
  unsigned short* wTl  = (unsigned short*)(ws + 393216);     //    393,216 B
  float* qw            = (float*)(ws + 67108864);            //  2,097,152 B
  unsigned short* vbw  = (unsigned short*)(ws + 69206016);   //  1,048,576 B
  unsigned short* qhb  = (unsigned short*)(ws + 70254592);   //  1,048,576 B
  unsigned short* qlb  = (unsigned short*)(ws + 71303168);   //  1,048,576 B
  unsigned short* khb  = (unsigned short*)(ws + 72351744);   //  1,048,576 B
  unsigned short* klb  = (unsigned short*)(ws + 73400320);   //  1,048,576 B
  float* Oh            = (float*)(ws + 74448896);            //  4,194,304 B
  float* ml2           = (float*)(ws + 78643200);            //    131,072 B
  // total ws usage: ~78.8 MB

  kconv_kernel<<<dim3(768), dim3(256), 0, stream>>>(wq, wk, wv, wTh, wTl);
  kproj_kernel<<<dim3(256), dim3(256), 0, stream>>>(x, wTh, wTl, bq, bk, bv,
                                                    qw, qhb, qlb, khb, klb, vbw);
  kqk_kernel<<<dim3(1024), dim3(256), 0, stream>>>(qhb, qlb, khb, klb, S0L);
  kfused<<<dim3(512), dim3(256), 0, stream>>>(qw, S0L, vbw, rel, Oh, ml2);
  kcomb<<<dim3(512), dim3(256), 0, stream>>>(Oh, ml2, O);
}